// Round 9
// baseline (157.629 us; speedup 1.0000x reference)
//
#include <hip/hip_runtime.h>
#include <hip/hip_bf16.h>

#define B_ROWS 4096
#define D_DIM  512
#define N_ROWS 8192   // 2B
#define BM 128
#define BN 128
#define BKB 128       // K-tile in BYTES (= fp8 elements); row stride 128B, 8x16B granules
#define NBLK (N_ROWS / BM)             // 64 row-blocks
#define NPAIR (NBLK * (NBLK + 1) / 2)  // 2080 upper-tri block pairs

typedef float f32x4 __attribute__((ext_vector_type(4)));
typedef int   v4i   __attribute__((ext_vector_type(4)));
typedef int   v8i   __attribute__((ext_vector_type(8)));

// ---------------------------------------------------------------------------
// Kernel 1: per-pair prep. Block r computes norms, pos[r] (fp32 exact),
// fp8-e4m3 normalized rows Z[r], Z[r+B]; zeroes row_sum and completion ctr.
// ---------------------------------------------------------------------------
__global__ __launch_bounds__(256) void prep_kernel(
    const float* __restrict__ poly, const float* __restrict__ cemb,
    unsigned char* __restrict__ Z, float* __restrict__ row_sum,
    float* __restrict__ pos, unsigned int* __restrict__ counter)
{
    const int r = blockIdx.x;
    const int t = threadIdx.x;
    const float* prow = poly + (size_t)r * D_DIM;
    const float* crow = cemb + (size_t)r * D_DIM;

    const float2 pv = *(const float2*)(prow + 2 * t);
    const float2 cv = *(const float2*)(crow + 2 * t);

    float ssp = pv.x * pv.x + pv.y * pv.y;
    float ssc = cv.x * cv.x + cv.y * cv.y;
    float dt  = pv.x * cv.x + pv.y * cv.y;

    #pragma unroll
    for (int m = 1; m < 64; m <<= 1) {
        ssp += __shfl_xor(ssp, m);
        ssc += __shfl_xor(ssc, m);
        dt  += __shfl_xor(dt,  m);
    }
    __shared__ float red[3][4];
    const int wave = t >> 6;
    if ((t & 63) == 0) { red[0][wave] = ssp; red[1][wave] = ssc; red[2][wave] = dt; }
    __syncthreads();
    ssp = red[0][0] + red[0][1] + red[0][2] + red[0][3];
    ssc = red[1][0] + red[1][1] + red[1][2] + red[1][3];
    dt  = red[2][0] + red[2][1] + red[2][2] + red[2][3];

    const float sp = 1.0f / fmaxf(sqrtf(ssp), 1e-12f);
    const float sc = 1.0f / fmaxf(sqrtf(ssc), 1e-12f);

    unsigned char* zp = Z + (size_t)r * D_DIM;
    unsigned char* zc = Z + (size_t)(r + B_ROWS) * D_DIM;
    const int pk = __builtin_amdgcn_cvt_pk_fp8_f32(pv.x * sp, pv.y * sp, 0, false);
    const int ck = __builtin_amdgcn_cvt_pk_fp8_f32(cv.x * sc, cv.y * sc, 0, false);
    *(unsigned short*)(zp + 2 * t) = (unsigned short)(pk & 0xffff);
    *(unsigned short*)(zc + 2 * t) = (unsigned short)(ck & 0xffff);

    if (t == 0) {
        pos[r] = dt * sp * sc;
        row_sum[2 * r]     = 0.0f;
        row_sum[2 * r + 1] = 0.0f;
        if (r == 0) *counter = 0u;
    }
}

// ---------------------------------------------------------------------------
// Kernel 2: symmetric sim = Z Z^T in fp8 via MX-scaled K=128 MFMA
// (mfma_scale_f32_16x16x128_f8f6f4, unit scales: e8m0 127 = 1.0; runs at
// ~2x non-scaled fp8 rate and 4x fewer instructions). Fragment = 32 B/lane,
// read as TWO ds_read_b128 from swizzled granules (2q)^(c&7), (2q+1)^(c&7)
// — the b128 pattern that measured 0 bank conflicts in rounds 2/5/7 (the
// round-8 b64 pattern cost 4 cyc/read in conflicts). Z = 4.2 MB fits
// per-XCD L2 (round-8 win: FETCH 95->17 MB). Strict gj>gi predicate;
// LDS-reduced epilogue; fence-free fused finalize (round-6 lesson).
// ---------------------------------------------------------------------------
__global__ __launch_bounds__(256) void sim_kernel(
    const unsigned char* __restrict__ Z, float* __restrict__ row_sum,
    const float* __restrict__ pos, float* __restrict__ out,
    unsigned int* __restrict__ counter)
{
    __shared__ __align__(16) unsigned char As[BM * BKB];   // 16 KB
    __shared__ __align__(16) unsigned char Bs[BN * BKB];   // 16 KB
    __shared__ float rAcc[BM];
    __shared__ float cAcc[BN];
    __shared__ unsigned int lastFlag;

    // decode blockIdx.x -> (bi, bj), bi <= bj < 64; C(b) = b*(129-b)/2
    const int t0 = blockIdx.x;
    int bi = (int)((129.0f - sqrtf(16641.0f - 8.0f * (float)t0)) * 0.5f);
    #define CFN(b) ((b) * (129 - (b)) / 2)
    while (CFN(bi + 1) <= t0) ++bi;
    while (CFN(bi) > t0) --bi;
    const int bj = bi + (t0 - CFN(bi));
    #undef CFN
    const bool diag = (bi == bj);

    const int ibase = bi * BM;
    const int jbase = bj * BN;
    const int tid   = threadIdx.x;

    const int srow = tid >> 3;                 // staging row within 32-row group
    const int gchk = (tid & 7) ^ (srow & 7);   // swizzled source granule (16B)

    const int wave = tid >> 6;
    const int lane = tid & 63;
    const int wi = (wave >> 1) * 64;
    const int wj = (wave & 1) * 64;
    const int quad = lane >> 4;
    const int c    = lane & 15;

    const int SCALE1 = 0x7f7f7f7f;             // e8m0 1.0 in every byte

    f32x4 acc[4][4] = {};

    for (int k0 = 0; k0 < D_DIM; k0 += BKB) {   // 4 iterations
        #pragma unroll
        for (int it = 0; it < 4; ++it) {
            const int row = it * 32 + srow;
            const unsigned char* ga = Z + (size_t)(ibase + row) * D_DIM + k0 + gchk * 16;
            __builtin_amdgcn_global_load_lds(
                (const __attribute__((address_space(1))) void*)ga,
                (__attribute__((address_space(3))) void*)(As + it * 4096 + tid * 16),
                16, 0, 0);
        }
        if (!diag) {
            #pragma unroll
            for (int it = 0; it < 4; ++it) {
                const int row = it * 32 + srow;
                const unsigned char* gb = Z + (size_t)(jbase + row) * D_DIM + k0 + gchk * 16;
                __builtin_amdgcn_global_load_lds(
                    (const __attribute__((address_space(1))) void*)gb,
                    (__attribute__((address_space(3))) void*)(Bs + it * 4096 + tid * 16),
                    16, 0, 0);
            }
        }
        __syncthreads();

        const unsigned char* bsrc = diag ? As : Bs;
        // Fragment: lane (c,quad) holds k-bytes [quad*32, quad*32+32) of its
        // row -> granules 2q, 2q+1, stored at swizzled slots ^(c&7).
        const int s0 = (2 * quad)     ^ (c & 7);
        const int s1 = (2 * quad + 1) ^ (c & 7);
        v8i a[4], b[4];
        #pragma unroll
        for (int ti = 0; ti < 4; ++ti) {
            const unsigned char* base = &As[(wi + ti * 16 + c) * BKB];
            const v4i lo = *(const v4i*)(base + s0 * 16);
            const v4i hi = *(const v4i*)(base + s1 * 16);
            a[ti] = __builtin_shufflevector(lo, hi, 0, 1, 2, 3, 4, 5, 6, 7);
        }
        #pragma unroll
        for (int tj = 0; tj < 4; ++tj) {
            const unsigned char* base = &bsrc[(wj + tj * 16 + c) * BKB];
            const v4i lo = *(const v4i*)(base + s0 * 16);
            const v4i hi = *(const v4i*)(base + s1 * 16);
            b[tj] = __builtin_shufflevector(lo, hi, 0, 1, 2, 3, 4, 5, 6, 7);
        }
        #pragma unroll
        for (int ti = 0; ti < 4; ++ti)
            #pragma unroll
            for (int tj = 0; tj < 4; ++tj)
                acc[ti][tj] = __builtin_amdgcn_mfma_scale_f32_16x16x128_f8f6f4(
                    a[ti], b[tj], acc[ti][tj],
                    0, 0,               // cbsz=fp8, blgp=fp8
                    0, SCALE1,          // A scale opsel, scale = 1.0
                    0, SCALE1);         // B scale opsel, scale = 1.0
        __syncthreads();
    }

    // ---- Epilogue: strict-upper exp(sim/T), pre-reduced in LDS ----
    if (tid < BM) { rAcc[tid] = 0.0f; cAcc[tid] = 0.0f; }
    __syncthreads();

    const float K2 = 2.885390081777927f;  // 2*log2(e) = 1/(T*ln2)
    float col[4] = {0.0f, 0.0f, 0.0f, 0.0f};
    #pragma unroll
    for (int ti = 0; ti < 4; ++ti) {
        const int li = wi + ti * 16 + quad * 4;
        #pragma unroll
        for (int r = 0; r < 4; ++r) {
            const int gi = ibase + li + r;
            float v = 0.0f;
            #pragma unroll
            for (int tj = 0; tj < 4; ++tj) {
                const int gj = jbase + wj + tj * 16 + c;
                const float e = (gj > gi) ? exp2f(K2 * acc[ti][tj][r]) : 0.0f;
                v += e;
                col[tj] += e;
            }
            v += __shfl_xor(v, 1);
            v += __shfl_xor(v, 2);
            v += __shfl_xor(v, 4);
            v += __shfl_xor(v, 8);
            if (c == 0)
                atomicAdd(&rAcc[li + r], v);
        }
    }
    #pragma unroll
    for (int tj = 0; tj < 4; ++tj) {
        float w = col[tj];
        w += __shfl_xor(w, 16);
        w += __shfl_xor(w, 32);
        if (quad == 0)
            atomicAdd(&cAcc[wj + tj * 16 + c], w);
    }
    __syncthreads();

    if (tid < BM)
        atomicAdd(&row_sum[ibase + tid], rAcc[tid]);
    else
        atomicAdd(&row_sum[jbase + tid - BM], cAcc[tid - BM]);

    // ---- Completion count; last block computes the loss (fence-free) ----
    __syncthreads();   // barrier implies vmcnt(0): this block's atomics issued
    if (tid == 0) {
        unsigned int old = __hip_atomic_fetch_add(
            counter, 1u, __ATOMIC_RELAXED, __HIP_MEMORY_SCOPE_AGENT);
        lastFlag = (old == NPAIR - 1) ? 1u : 0u;
    }
    __syncthreads();
    if (lastFlag) {
        float accL = 0.0f, accP = 0.0f;
        for (int i = tid; i < N_ROWS; i += 256) {
            const float rs = __hip_atomic_load(
                &row_sum[i], __ATOMIC_RELAXED, __HIP_MEMORY_SCOPE_AGENT);
            accL += __logf(rs);
        }
        for (int r = tid; r < B_ROWS; r += 256)
            accP += pos[r];
        #pragma unroll
        for (int m = 1; m < 64; m <<= 1) {
            accL += __shfl_xor(accL, m);
            accP += __shfl_xor(accP, m);
        }
        if (lane == 0) { rAcc[wave] = accL; cAcc[wave] = accP; }
        __syncthreads();
        if (tid == 0) {
            float L = 0.0f, P = 0.0f;
            #pragma unroll
            for (int w = 0; w < 4; ++w) { L += rAcc[w]; P += cAcc[w]; }
            out[0] = (L - 4.0f * P) / (float)N_ROWS;
        }
    }
}

extern "C" void kernel_launch(void* const* d_in, const int* in_sizes, int n_in,
                              void* d_out, int out_size, void* d_ws, size_t ws_size,
                              hipStream_t stream) {
    const float* poly = (const float*)d_in[0];
    const float* cemb = (const float*)d_in[1];

    unsigned char* Z       = (unsigned char*)d_ws;
    float*         row_sum = (float*)((char*)d_ws + (size_t)N_ROWS * D_DIM);
    float*         pos     = row_sum + N_ROWS;
    unsigned int*  counter = (unsigned int*)(pos + B_ROWS);
    float*         out     = (float*)d_out;

    prep_kernel<<<B_ROWS, 256, 0, stream>>>(poly, cemb, Z, row_sum, pos, counter);
    sim_kernel<<<NPAIR, 256, 0, stream>>>(Z, row_sum, pos, out, counter);
}

// Round 11
// 134.287 us; speedup vs baseline: 1.1738x; 1.1738x over previous
//
#include <hip/hip_runtime.h>
#include <hip/hip_bf16.h>

#define B_ROWS 4096
#define D_DIM  512
#define N_ROWS 8192   // 2B
#define BM 128
#define BN 128
#define BKB 128       // K-tile in BYTES (= fp8 elements); row stride 128B = 8 granules
#define NBLK (N_ROWS / BM)             // 64 row-blocks
#define NPAIR (NBLK * (NBLK + 1) / 2)  // 2080 upper-tri block pairs

typedef float f32x4 __attribute__((ext_vector_type(4)));
typedef long  longx2 __attribute__((ext_vector_type(2)));

// ---------------------------------------------------------------------------
// Kernel 1: per-pair prep. Block r computes norms, pos[r] (fp32 exact),
// fp8-e4m3 normalized rows Z[r], Z[r+B]; zeroes row_sum and completion ctr.
// ---------------------------------------------------------------------------
__global__ __launch_bounds__(256) void prep_kernel(
    const float* __restrict__ poly, const float* __restrict__ cemb,
    unsigned char* __restrict__ Z, float* __restrict__ row_sum,
    float* __restrict__ pos, unsigned int* __restrict__ counter)
{
    const int r = blockIdx.x;
    const int t = threadIdx.x;
    const float* prow = poly + (size_t)r * D_DIM;
    const float* crow = cemb + (size_t)r * D_DIM;

    const float2 pv = *(const float2*)(prow + 2 * t);
    const float2 cv = *(const float2*)(crow + 2 * t);

    float ssp = pv.x * pv.x + pv.y * pv.y;
    float ssc = cv.x * cv.x + cv.y * cv.y;
    float dt  = pv.x * cv.x + pv.y * cv.y;

    #pragma unroll
    for (int m = 1; m < 64; m <<= 1) {
        ssp += __shfl_xor(ssp, m);
        ssc += __shfl_xor(ssc, m);
        dt  += __shfl_xor(dt,  m);
    }
    __shared__ float red[3][4];
    const int wave = t >> 6;
    if ((t & 63) == 0) { red[0][wave] = ssp; red[1][wave] = ssc; red[2][wave] = dt; }
    __syncthreads();
    ssp = red[0][0] + red[0][1] + red[0][2] + red[0][3];
    ssc = red[1][0] + red[1][1] + red[1][2] + red[1][3];
    dt  = red[2][0] + red[2][1] + red[2][2] + red[2][3];

    const float sp = 1.0f / fmaxf(sqrtf(ssp), 1e-12f);
    const float sc = 1.0f / fmaxf(sqrtf(ssc), 1e-12f);

    unsigned char* zp = Z + (size_t)r * D_DIM;
    unsigned char* zc = Z + (size_t)(r + B_ROWS) * D_DIM;
    const int pk = __builtin_amdgcn_cvt_pk_fp8_f32(pv.x * sp, pv.y * sp, 0, false);
    const int ck = __builtin_amdgcn_cvt_pk_fp8_f32(cv.x * sc, cv.y * sc, 0, false);
    *(unsigned short*)(zp + 2 * t) = (unsigned short)(pk & 0xffff);
    *(unsigned short*)(zc + 2 * t) = (unsigned short)(ck & 0xffff);

    if (t == 0) {
        pos[r] = dt * sp * sc;
        row_sum[2 * r]     = 0.0f;
        row_sum[2 * r + 1] = 0.0f;
        if (r == 0) *counter = 0u;
    }
}

// ---------------------------------------------------------------------------
// Kernel 2: symmetric sim = Z Z^T in fp8 (mfma_f32_16x16x32_fp8_fp8).
// Z = 4.2 MB fits per-XCD L2 (round-8 win: FETCH 95->17 MB). 128x128 tiles
// over upper-tri pairs, BK=128 bytes (4 k0 iters).
// Fragment reads use a k-PERMUTATION: MFMA sums over k, so A and B may share
// any bijective k-assignment. Lane (c,q) reads granules q and 4+q of its row
// as TWO ds_read_b128 at swizzled slots q^(c&7), (4+q)^(c&7) — the
// 8-lanes-per-slot b128 shape that measured 0 conflicts in rounds 2/5/7
// (round-8's b64 pattern cost 4.26e6 conflict-cycles). The four 8-byte
// halves feed four K=32 MFMAs covering k in [0,128) exactly, identically
// for A and B -> result unchanged.
// Strict gj>gi predicate (diagonal excluded exactly); LDS-reduced epilogue;
// fence-free fused finalize (round-6 lesson: NO __threadfence; round-10
// lesson: NO cooperative launch in this harness).
// ---------------------------------------------------------------------------
__global__ __launch_bounds__(256) void sim_kernel(
    const unsigned char* __restrict__ Z, float* __restrict__ row_sum,
    const float* __restrict__ pos, float* __restrict__ out,
    unsigned int* __restrict__ counter)
{
    __shared__ __align__(16) unsigned char As[BM * BKB];   // 16 KB
    __shared__ __align__(16) unsigned char Bs[BN * BKB];   // 16 KB
    __shared__ float rAcc[BM];
    __shared__ float cAcc[BN];
    __shared__ unsigned int lastFlag;

    // decode blockIdx.x -> (bi, bj), bi <= bj < 64; C(b) = b*(129-b)/2
    const int t0 = blockIdx.x;
    int bi = (int)((129.0f - sqrtf(16641.0f - 8.0f * (float)t0)) * 0.5f);
    #define CFN(b) ((b) * (129 - (b)) / 2)
    while (CFN(bi + 1) <= t0) ++bi;
    while (CFN(bi) > t0) --bi;
    const int bj = bi + (t0 - CFN(bi));
    #undef CFN
    const bool diag = (bi == bj);

    const int ibase = bi * BM;
    const int jbase = bj * BN;
    const int tid   = threadIdx.x;

    const int srow = tid >> 3;                 // staging row within 32-row group
    const int gchk = (tid & 7) ^ (srow & 7);   // swizzled source granule (16B)

    const int wave = tid >> 6;
    const int lane = tid & 63;
    const int wi = (wave >> 1) * 64;
    const int wj = (wave & 1) * 64;
    const int quad = lane >> 4;
    const int c    = lane & 15;
    const int c7   = c & 7;
    const int sLo  = quad ^ c7;        // slot holding global granule `quad`
    const int sHi  = (4 + quad) ^ c7;  // slot holding global granule `4+quad`

    f32x4 acc[4][4] = {};

    for (int k0 = 0; k0 < D_DIM; k0 += BKB) {   // 4 iterations
        #pragma unroll
        for (int it = 0; it < 4; ++it) {
            const int row = it * 32 + srow;
            const unsigned char* ga = Z + (size_t)(ibase + row) * D_DIM + k0 + gchk * 16;
            __builtin_amdgcn_global_load_lds(
                (const __attribute__((address_space(1))) void*)ga,
                (__attribute__((address_space(3))) void*)(As + it * 4096 + tid * 16),
                16, 0, 0);
        }
        if (!diag) {
            #pragma unroll
            for (int it = 0; it < 4; ++it) {
                const int row = it * 32 + srow;
                const unsigned char* gb = Z + (size_t)(jbase + row) * D_DIM + k0 + gchk * 16;
                __builtin_amdgcn_global_load_lds(
                    (const __attribute__((address_space(1))) void*)gb,
                    (__attribute__((address_space(3))) void*)(Bs + it * 4096 + tid * 16),
                    16, 0, 0);
            }
        }
        __syncthreads();

        const unsigned char* bsrc = diag ? As : Bs;
        // lo granules: global k-bytes [16q, 16q+16)
        {
            longx2 a[4], b[4];
            #pragma unroll
            for (int ti = 0; ti < 4; ++ti)
                a[ti] = *(const longx2*)&As[(wi + ti * 16 + c) * BKB + sLo * 16];
            #pragma unroll
            for (int tj = 0; tj < 4; ++tj)
                b[tj] = *(const longx2*)&bsrc[(wj + tj * 16 + c) * BKB + sLo * 16];
            #pragma unroll
            for (int ti = 0; ti < 4; ++ti)
                #pragma unroll
                for (int tj = 0; tj < 4; ++tj) {
                    acc[ti][tj] = __builtin_amdgcn_mfma_f32_16x16x32_fp8_fp8(
                        a[ti].x, b[tj].x, acc[ti][tj], 0, 0, 0);
                    acc[ti][tj] = __builtin_amdgcn_mfma_f32_16x16x32_fp8_fp8(
                        a[ti].y, b[tj].y, acc[ti][tj], 0, 0, 0);
                }
        }
        // hi granules: global k-bytes [64+16q, 64+16q+16)
        {
            longx2 a[4], b[4];
            #pragma unroll
            for (int ti = 0; ti < 4; ++ti)
                a[ti] = *(const longx2*)&As[(wi + ti * 16 + c) * BKB + sHi * 16];
            #pragma unroll
            for (int tj = 0; tj < 4; ++tj)
                b[tj] = *(const longx2*)&bsrc[(wj + tj * 16 + c) * BKB + sHi * 16];
            #pragma unroll
            for (int ti = 0; ti < 4; ++ti)
                #pragma unroll
                for (int tj = 0; tj < 4; ++tj) {
                    acc[ti][tj] = __builtin_amdgcn_mfma_f32_16x16x32_fp8_fp8(
                        a[ti].x, b[tj].x, acc[ti][tj], 0, 0, 0);
                    acc[ti][tj] = __builtin_amdgcn_mfma_f32_16x16x32_fp8_fp8(
                        a[ti].y, b[tj].y, acc[ti][tj], 0, 0, 0);
                }
        }
        __syncthreads();
    }

    // ---- Epilogue: strict-upper exp(sim/T), pre-reduced in LDS ----
    if (tid < BM) { rAcc[tid] = 0.0f; cAcc[tid] = 0.0f; }
    __syncthreads();

    const float K2 = 2.885390081777927f;  // 2*log2(e) = 1/(T*ln2)
    float col[4] = {0.0f, 0.0f, 0.0f, 0.0f};
    #pragma unroll
    for (int ti = 0; ti < 4; ++ti) {
        const int li = wi + ti * 16 + quad * 4;
        #pragma unroll
        for (int r = 0; r < 4; ++r) {
            const int gi = ibase + li + r;
            float v = 0.0f;
            #pragma unroll
            for (int tj = 0; tj < 4; ++tj) {
                const int gj = jbase + wj + tj * 16 + c;
                const float e = (gj > gi) ? exp2f(K2 * acc[ti][tj][r]) : 0.0f;
                v += e;
                col[tj] += e;
            }
            v += __shfl_xor(v, 1);
            v += __shfl_xor(v, 2);
            v += __shfl_xor(v, 4);
            v += __shfl_xor(v, 8);
            if (c == 0)
                atomicAdd(&rAcc[li + r], v);
        }
    }
    #pragma unroll
    for (int tj = 0; tj < 4; ++tj) {
        float w = col[tj];
        w += __shfl_xor(w, 16);
        w += __shfl_xor(w, 32);
        if (quad == 0)
            atomicAdd(&cAcc[wj + tj * 16 + c], w);
    }
    __syncthreads();

    if (tid < BM)
        atomicAdd(&row_sum[ibase + tid], rAcc[tid]);
    else
        atomicAdd(&row_sum[jbase + tid - BM], cAcc[tid - BM]);

    // ---- Completion count; last block computes the loss (fence-free) ----
    __syncthreads();   // barrier implies vmcnt(0): this block's atomics issued
    if (tid == 0) {
        unsigned int old = __hip_atomic_fetch_add(
            counter, 1u, __ATOMIC_RELAXED, __HIP_MEMORY_SCOPE_AGENT);
        lastFlag = (old == NPAIR - 1) ? 1u : 0u;
    }
    __syncthreads();
    if (lastFlag) {
        float accL = 0.0f, accP = 0.0f;
        for (int i = tid; i < N_ROWS; i += 256) {
            const float rs = __hip_atomic_load(
                &row_sum[i], __ATOMIC_RELAXED, __HIP_MEMORY_SCOPE_AGENT);
            accL += __logf(rs);
        }
        for (int r = tid; r < B_ROWS; r += 256)
            accP += pos[r];
        #pragma unroll
        for (int m = 1; m < 64; m <<= 1) {
            accL += __shfl_xor(accL, m);
            accP += __shfl_xor(accP, m);
        }
        if (lane == 0) { rAcc[wave] = accL; cAcc[wave] = accP; }
        __syncthreads();
        if (tid == 0) {
            float L = 0.0f, P = 0.0f;
            #pragma unroll
            for (int w = 0; w < 4; ++w) { L += rAcc[w]; P += cAcc[w]; }
            out[0] = (L - 4.0f * P) / (float)N_ROWS;
        }
    }
}

extern "C" void kernel_launch(void* const* d_in, const int* in_sizes, int n_in,
                              void* d_out, int out_size, void* d_ws, size_t ws_size,
                              hipStream_t stream) {
    const float* poly = (const float*)d_in[0];
    const float* cemb = (const float*)d_in[1];

    unsigned char* Z       = (unsigned char*)d_ws;
    float*         row_sum = (float*)((char*)d_ws + (size_t)N_ROWS * D_DIM);
    float*         pos     = row_sum + N_ROWS;
    unsigned int*  counter = (unsigned int*)(pos + B_ROWS);
    float*         out     = (float*)d_out;

    prep_kernel<<<B_ROWS, 256, 0, stream>>>(poly, cemb, Z, row_sum, pos, counter);
    sim_kernel<<<NPAIR, 256, 0, stream>>>(Z, row_sum, pos, out, counter);
}